// Round 1
// baseline (427.534 us; speedup 1.0000x reference)
//
#include <hip/hip_runtime.h>
#include <hip/hip_bf16.h>
#include <cstddef>

// Hyena1D: y = irfft(rfft(x, axis=1) * H) * amp_gain, H real per (bin, channel).
// Implemented as full complex 4096-FFT via four-step (64x64) decomposition,
// H extended symmetrically: Hfull[k] = H[min(k, 4096-k)] (real => conj symmetry
// preserved => output real; identical to irfft(rfft(x)*H)).
//
// ws layout: G = float2[B][64][64][D] = 128 MB (requires ws_size >= 134217728).
// h (2049x32) and Hbuf (2049x1024) are staged inside d_out (fully overwritten
// by the final kernel afterwards).

#define B_ 4
#define T_ 4096
#define D_ 1024
#define NBINS 2049

// W64 twiddle table: WC[j] = cos(pi*j/32), WS[j] = sin(pi*j/32), j in [0,32)
constexpr float WC[32] = {
    1.0f, 0.9951847266721969f, 0.9807852804032304f, 0.9569403357322088f,
    0.9238795325112867f, 0.8819212643483551f, 0.8314696123025452f, 0.7730104533627370f,
    0.7071067811865476f, 0.6343932841636455f, 0.5555702330196022f, 0.4713967368259976f,
    0.3826834323650898f, 0.2902846772544623f, 0.1950903220161283f, 0.0980171403295606f,
    0.0f, -0.0980171403295606f, -0.1950903220161283f, -0.2902846772544623f,
    -0.3826834323650898f, -0.4713967368259976f, -0.5555702330196022f, -0.6343932841636455f,
    -0.7071067811865476f, -0.7730104533627370f, -0.8314696123025452f, -0.8819212643483551f,
    -0.9238795325112867f, -0.9569403357322088f, -0.9807852804032304f, -0.9951847266721969f};
constexpr float WS[32] = {
    0.0f, 0.0980171403295606f, 0.1950903220161283f, 0.2902846772544623f,
    0.3826834323650898f, 0.4713967368259976f, 0.5555702330196022f, 0.6343932841636455f,
    0.7071067811865476f, 0.7730104533627370f, 0.8314696123025452f, 0.8819212643483551f,
    0.9238795325112867f, 0.9569403357322088f, 0.9807852804032304f, 0.9951847266721969f,
    1.0f, 0.9951847266721969f, 0.9807852804032304f, 0.9569403357322088f,
    0.9238795325112867f, 0.8819212643483551f, 0.8314696123025452f, 0.7730104533627370f,
    0.7071067811865476f, 0.6343932841636455f, 0.5555702330196022f, 0.4713967368259976f,
    0.3826834323650898f, 0.2902846772544623f, 0.1950903220161283f, 0.0980171403295606f};

// In-register 64-point complex FFT, fully unrolled radix-2 DIT.
// SGN = -1: forward (e^{-i}), SGN = +1: inverse (e^{+i}), unnormalized.
template <int SGN>
__device__ __forceinline__ void fft64(float (&vr)[64], float (&vi)[64]) {
  // bit reversal (6 bits)
#pragma unroll
  for (int i = 0; i < 64; ++i) {
    const int j = ((i & 1) << 5) | ((i & 2) << 3) | ((i & 4) << 1) |
                  ((i & 8) >> 1) | ((i & 16) >> 3) | ((i & 32) >> 5);
    if (j > i) {
      float t = vr[i]; vr[i] = vr[j]; vr[j] = t;
      t = vi[i]; vi[i] = vi[j]; vi[j] = t;
    }
  }
#pragma unroll
  for (int s = 1; s <= 6; ++s) {
    const int L = 1 << s;
    const int hh = L >> 1;
    const int step = 64 >> s;
#pragma unroll
    for (int k0 = 0; k0 < 64; k0 += L) {
#pragma unroll
      for (int j = 0; j < hh; ++j) {
        const float wr = WC[j * step];
        const float wi = (float)SGN * WS[j * step];
        const int ia = k0 + j, ib = k0 + j + hh;
        const float tr = wr * vr[ib] - wi * vi[ib];
        const float ti = wr * vi[ib] + wi * vr[ib];
        vr[ib] = vr[ia] - tr;
        vi[ib] = vi[ia] - ti;
        vr[ia] += tr;
        vi[ia] += ti;
      }
    }
  }
}

// ---- filter MLP ----
__global__ void k_filter_h(const float* __restrict__ W1, const float* __restrict__ b1,
                           float* __restrict__ h) {
  const int bin = blockIdx.x * 256 + threadIdx.x;
  if (bin >= NBINS) return;
  constexpr float invf[8] = {1.0f, 0.31622776601683794f, 0.1f, 0.031622776601683794f,
                             0.01f, 3.1622776601683794e-3f, 1.0e-3f, 3.1622776601683794e-4f};
  float pe[16];
#pragma unroll
  for (int i = 0; i < 8; ++i) {
    const float a = (float)bin * invf[i];
    pe[2 * i] = sinf(a);
    pe[2 * i + 1] = cosf(a);
  }
#pragma unroll
  for (int m = 0; m < 32; ++m) {
    float s = b1[m];
#pragma unroll
    for (int i = 0; i < 16; ++i) s += pe[i] * W1[i * 32 + m];
    h[bin * 32 + m] = s / (1.0f + expf(-s));  // silu
  }
}

__global__ void k_filter_H(const float* __restrict__ h, const float* __restrict__ W2,
                           const float* __restrict__ b2, float* __restrict__ Hb) {
  const int d = blockIdx.x * 256 + threadIdx.x;
  const int bin = blockIdx.y;
  float s = b2[d];
#pragma unroll
  for (int m = 0; m < 32; ++m) s += h[bin * 32 + m] * W2[(size_t)m * D_ + d];
  Hb[(size_t)bin * D_ + d] = s;
}

// ---- stage 1: FFT over n2 (t = n1 + 64*n2) + twiddle W_4096^{n1*k2} ----
__global__ __launch_bounds__(256, 2) void k_fft_stage1(const float* __restrict__ x,
                                                       float2* __restrict__ G) {
  const int d = blockIdx.x * 256 + threadIdx.x;
  const int n1 = blockIdx.y;
  const int b = blockIdx.z;
  float vr[64], vi[64];
  const float* xp = x + (((size_t)b * T_ + n1) * D_) + d;
#pragma unroll
  for (int n2 = 0; n2 < 64; ++n2) {
    vr[n2] = xp[(size_t)n2 * 64 * D_];
    vi[n2] = 0.0f;
  }
  fft64<-1>(vr, vi);
  const float base = -(6.28318530717958647692f / 4096.0f) * (float)n1;
#pragma unroll
  for (int k2 = 1; k2 < 64; ++k2) {
    float sn, cs;
    __sincosf(base * (float)k2, &sn, &cs);
    const float r = vr[k2] * cs - vi[k2] * sn;
    const float i = vr[k2] * sn + vi[k2] * cs;
    vr[k2] = r;
    vi[k2] = i;
  }
  float2* gp = G + (((size_t)b * 64 + n1) * 64) * D_ + d;
#pragma unroll
  for (int k2 = 0; k2 < 64; ++k2) gp[(size_t)k2 * D_] = make_float2(vr[k2], vi[k2]);
}

// ---- stage 2: FFT over n1 -> X[k2+64*k1]; * Hfull; inverse FFT over k1;
//      * W_4096^{-n1*k2}; in-place (per-thread addresses only) ----
__global__ __launch_bounds__(256, 2) void k_fft_stage2(float2* __restrict__ G,
                                                       const float* __restrict__ Hb) {
  const int d = blockIdx.x * 256 + threadIdx.x;
  const int k2 = blockIdx.y;
  const int b = blockIdx.z;
  float vr[64], vi[64];
  float2* gp = G + (((size_t)b * 64) * 64 + k2) * D_ + d;  // + n1*64*D_
#pragma unroll
  for (int n1 = 0; n1 < 64; ++n1) {
    const float2 t = gp[(size_t)n1 * 64 * D_];
    vr[n1] = t.x;
    vi[n1] = t.y;
  }
  fft64<-1>(vr, vi);
#pragma unroll
  for (int k1 = 0; k1 < 64; ++k1) {
    const int k = k2 + 64 * k1;
    const int km = (k <= 2048) ? k : (4096 - k);
    const float Hv = Hb[(size_t)km * D_ + d];
    vr[k1] *= Hv;
    vi[k1] *= Hv;
  }
  fft64<1>(vr, vi);
  const float base = (6.28318530717958647692f / 4096.0f) * (float)k2;
#pragma unroll
  for (int n1 = 1; n1 < 64; ++n1) {
    float sn, cs;
    __sincosf(base * (float)n1, &sn, &cs);
    const float r = vr[n1] * cs - vi[n1] * sn;
    const float i = vr[n1] * sn + vi[n1] * cs;
    vr[n1] = r;
    vi[n1] = i;
  }
#pragma unroll
  for (int n1 = 0; n1 < 64; ++n1) gp[(size_t)n1 * 64 * D_] = make_float2(vr[n1], vi[n1]);
}

// ---- stage 3: inverse FFT over k2 -> y[n1 + 64*n2], scale + amp_gain ----
__global__ __launch_bounds__(256, 2) void k_fft_stage3(const float2* __restrict__ G,
                                                       const float* __restrict__ amp,
                                                       float* __restrict__ out) {
  const int d = blockIdx.x * 256 + threadIdx.x;
  const int n1 = blockIdx.y;
  const int b = blockIdx.z;
  float vr[64], vi[64];
  const float2* gp = G + (((size_t)b * 64 + n1) * 64) * D_ + d;
#pragma unroll
  for (int k2 = 0; k2 < 64; ++k2) {
    const float2 t = gp[(size_t)k2 * D_];
    vr[k2] = t.x;
    vi[k2] = t.y;
  }
  fft64<1>(vr, vi);
  const float scale = amp[d] * (1.0f / 4096.0f);
  float* op = out + (((size_t)b * T_ + n1) * D_) + d;
#pragma unroll
  for (int n2 = 0; n2 < 64; ++n2) op[(size_t)n2 * 64 * D_] = vr[n2] * scale;
}

extern "C" void kernel_launch(void* const* d_in, const int* in_sizes, int n_in,
                              void* d_out, int out_size, void* d_ws, size_t ws_size,
                              hipStream_t stream) {
  const float* x = (const float*)d_in[0];
  const float* W1 = (const float*)d_in[1];
  const float* b1 = (const float*)d_in[2];
  const float* W2 = (const float*)d_in[3];
  const float* b2 = (const float*)d_in[4];
  const float* amp = (const float*)d_in[5];
  float* out = (float*)d_out;

  // Stage MLP outputs inside d_out (fully overwritten by k_fft_stage3 later):
  float* h = out;              // 2049*32   = 65,568 floats
  float* Hb = out + 65568;     // 2049*1024 = 2,098,176 floats (ends < out_size)
  float2* G = (float2*)d_ws;   // [4][64][64][1024] float2 = 134,217,728 bytes

  k_filter_h<<<dim3((NBINS + 255) / 256), 256, 0, stream>>>(W1, b1, h);
  k_filter_H<<<dim3(D_ / 256, NBINS), 256, 0, stream>>>(h, W2, b2, Hb);
  k_fft_stage1<<<dim3(D_ / 256, 64, B_), 256, 0, stream>>>(x, G);
  k_fft_stage2<<<dim3(D_ / 256, 64, B_), 256, 0, stream>>>(G, Hb);
  k_fft_stage3<<<dim3(D_ / 256, 64, B_), 256, 0, stream>>>(G, amp, out);
}

// Round 2
// 230.619 us; speedup vs baseline: 1.8539x; 1.8539x over previous
//
#include <hip/hip_runtime.h>
#include <hip/hip_bf16.h>
#include <cstddef>

// Hyena1D: y = irfft(rfft(x, axis=1) * H) * amp_gain, H real per (bin, channel).
// Full complex 4096-FFT via four-step (64x64) decomposition; H extended
// symmetrically Hfull[k] = H[min(k, 4096-k)] (real, conj-symmetric => output
// real; identical to irfft(rfft(x)*H)).
//
// ws layout: G = float2[B][64][64][D] = 128 MB (requires ws_size >= 134217728).
// h (2049x32) and Hbuf (2049x1024) staged inside d_out (fully overwritten by
// the final kernel).
//
// launch_bounds(256,1): vr[64]+vi[64] = 128 VGPRs of live data per thread;
// (256,2) capped the allocator at 128 VGPRs -> heavy scratch spill (rocprof:
// WRITE_SIZE 565 MB vs 134 MB ideal). 1 wave/EU floor allows 256 VGPRs, no
// spill; 64 independent coalesced loads/thread keep MLP high at low occupancy.

#define B_ 4
#define T_ 4096
#define D_ 1024
#define NBINS 2049

constexpr float WC[32] = {
    1.0f, 0.9951847266721969f, 0.9807852804032304f, 0.9569403357322088f,
    0.9238795325112867f, 0.8819212643483551f, 0.8314696123025452f, 0.7730104533627370f,
    0.7071067811865476f, 0.6343932841636455f, 0.5555702330196022f, 0.4713967368259976f,
    0.3826834323650898f, 0.2902846772544623f, 0.1950903220161283f, 0.0980171403295606f,
    0.0f, -0.0980171403295606f, -0.1950903220161283f, -0.2902846772544623f,
    -0.3826834323650898f, -0.4713967368259976f, -0.5555702330196022f, -0.6343932841636455f,
    -0.7071067811865476f, -0.7730104533627370f, -0.8314696123025452f, -0.8819212643483551f,
    -0.9238795325112867f, -0.9569403357322088f, -0.9807852804032304f, -0.9951847266721969f};
constexpr float WS[32] = {
    0.0f, 0.0980171403295606f, 0.1950903220161283f, 0.2902846772544623f,
    0.3826834323650898f, 0.4713967368259976f, 0.5555702330196022f, 0.6343932841636455f,
    0.7071067811865476f, 0.7730104533627370f, 0.8314696123025452f, 0.8819212643483551f,
    0.9238795325112867f, 0.9569403357322088f, 0.9807852804032304f, 0.9951847266721969f,
    1.0f, 0.9951847266721969f, 0.9807852804032304f, 0.9569403357322088f,
    0.9238795325112867f, 0.8819212643483551f, 0.8314696123025452f, 0.7730104533627370f,
    0.7071067811865476f, 0.6343932841636455f, 0.5555702330196022f, 0.4713967368259976f,
    0.3826834323650898f, 0.2902846772544623f, 0.1950903220161283f, 0.0980171403295606f};

template <int SGN>
__device__ __forceinline__ void fft64(float (&vr)[64], float (&vi)[64]) {
#pragma unroll
  for (int i = 0; i < 64; ++i) {
    const int j = ((i & 1) << 5) | ((i & 2) << 3) | ((i & 4) << 1) |
                  ((i & 8) >> 1) | ((i & 16) >> 3) | ((i & 32) >> 5);
    if (j > i) {
      float t = vr[i]; vr[i] = vr[j]; vr[j] = t;
      t = vi[i]; vi[i] = vi[j]; vi[j] = t;
    }
  }
#pragma unroll
  for (int s = 1; s <= 6; ++s) {
    const int L = 1 << s;
    const int hh = L >> 1;
    const int step = 64 >> s;
#pragma unroll
    for (int k0 = 0; k0 < 64; k0 += L) {
#pragma unroll
      for (int j = 0; j < hh; ++j) {
        const float wr = WC[j * step];
        const float wi = (float)SGN * WS[j * step];
        const int ia = k0 + j, ib = k0 + j + hh;
        const float tr = wr * vr[ib] - wi * vi[ib];
        const float ti = wr * vi[ib] + wi * vr[ib];
        vr[ib] = vr[ia] - tr;
        vi[ib] = vi[ia] - ti;
        vr[ia] += tr;
        vi[ia] += ti;
      }
    }
  }
}

// ---- filter MLP ----
__global__ void k_filter_h(const float* __restrict__ W1, const float* __restrict__ b1,
                           float* __restrict__ h) {
  const int bin = blockIdx.x * 256 + threadIdx.x;
  if (bin >= NBINS) return;
  constexpr float invf[8] = {1.0f, 0.31622776601683794f, 0.1f, 0.031622776601683794f,
                             0.01f, 3.1622776601683794e-3f, 1.0e-3f, 3.1622776601683794e-4f};
  float pe[16];
#pragma unroll
  for (int i = 0; i < 8; ++i) {
    const float a = (float)bin * invf[i];
    pe[2 * i] = sinf(a);
    pe[2 * i + 1] = cosf(a);
  }
#pragma unroll
  for (int m = 0; m < 32; ++m) {
    float s = b1[m];
#pragma unroll
    for (int i = 0; i < 16; ++i) s += pe[i] * W1[i * 32 + m];
    h[bin * 32 + m] = s / (1.0f + expf(-s));  // silu
  }
}

__global__ void k_filter_H(const float* __restrict__ h, const float* __restrict__ W2,
                           const float* __restrict__ b2, float* __restrict__ Hb) {
  const int d = blockIdx.x * 256 + threadIdx.x;
  const int bin = blockIdx.y;
  float s = b2[d];
#pragma unroll
  for (int m = 0; m < 32; ++m) s += h[bin * 32 + m] * W2[(size_t)m * D_ + d];
  Hb[(size_t)bin * D_ + d] = s;
}

// ---- stage 1: FFT over n2 (t = n1 + 64*n2) + twiddle W_4096^{n1*k2} ----
__global__ __launch_bounds__(256, 1) void k_fft_stage1(const float* __restrict__ x,
                                                       float2* __restrict__ G) {
  const int d = blockIdx.x * 256 + threadIdx.x;
  const int n1 = blockIdx.y;
  const int b = blockIdx.z;
  float vr[64], vi[64];
  const float* xp = x + (((size_t)b * T_ + n1) * D_) + d;
#pragma unroll
  for (int n2 = 0; n2 < 64; ++n2) {
    vr[n2] = xp[(size_t)n2 * 64 * D_];
    vi[n2] = 0.0f;
  }
  fft64<-1>(vr, vi);
  const float base = -(6.28318530717958647692f / 4096.0f) * (float)n1;
#pragma unroll
  for (int k2 = 1; k2 < 64; ++k2) {
    float sn, cs;
    __sincosf(base * (float)k2, &sn, &cs);
    const float r = vr[k2] * cs - vi[k2] * sn;
    const float i = vr[k2] * sn + vi[k2] * cs;
    vr[k2] = r;
    vi[k2] = i;
  }
  float2* gp = G + (((size_t)b * 64 + n1) * 64) * D_ + d;
#pragma unroll
  for (int k2 = 0; k2 < 64; ++k2) gp[(size_t)k2 * D_] = make_float2(vr[k2], vi[k2]);
}

// ---- stage 2: FFT over n1 -> X[k2+64*k1]; * Hfull; inverse FFT over k1;
//      * W_4096^{-n1*k2}; in-place (per-thread addresses only) ----
__global__ __launch_bounds__(256, 1) void k_fft_stage2(float2* __restrict__ G,
                                                       const float* __restrict__ Hb) {
  const int d = blockIdx.x * 256 + threadIdx.x;
  const int k2 = blockIdx.y;
  const int b = blockIdx.z;
  float vr[64], vi[64];
  float2* gp = G + (((size_t)b * 64) * 64 + k2) * D_ + d;  // + n1*64*D_
#pragma unroll
  for (int n1 = 0; n1 < 64; ++n1) {
    const float2 t = gp[(size_t)n1 * 64 * D_];
    vr[n1] = t.x;
    vi[n1] = t.y;
  }
  fft64<-1>(vr, vi);
#pragma unroll
  for (int k1 = 0; k1 < 64; ++k1) {
    const int k = k2 + 64 * k1;
    const int km = (k <= 2048) ? k : (4096 - k);
    const float Hv = Hb[(size_t)km * D_ + d];
    vr[k1] *= Hv;
    vi[k1] *= Hv;
  }
  fft64<1>(vr, vi);
  const float base = (6.28318530717958647692f / 4096.0f) * (float)k2;
#pragma unroll
  for (int n1 = 1; n1 < 64; ++n1) {
    float sn, cs;
    __sincosf(base * (float)n1, &sn, &cs);
    const float r = vr[n1] * cs - vi[n1] * sn;
    const float i = vr[n1] * sn + vi[n1] * cs;
    vr[n1] = r;
    vi[n1] = i;
  }
#pragma unroll
  for (int n1 = 0; n1 < 64; ++n1) gp[(size_t)n1 * 64 * D_] = make_float2(vr[n1], vi[n1]);
}

// ---- stage 3: inverse FFT over k2 -> y[n1 + 64*n2], scale + amp_gain ----
__global__ __launch_bounds__(256, 1) void k_fft_stage3(const float2* __restrict__ G,
                                                       const float* __restrict__ amp,
                                                       float* __restrict__ out) {
  const int d = blockIdx.x * 256 + threadIdx.x;
  const int n1 = blockIdx.y;
  const int b = blockIdx.z;
  float vr[64], vi[64];
  const float2* gp = G + (((size_t)b * 64 + n1) * 64) * D_ + d;
#pragma unroll
  for (int k2 = 0; k2 < 64; ++k2) {
    const float2 t = gp[(size_t)k2 * D_];
    vr[k2] = t.x;
    vi[k2] = t.y;
  }
  fft64<1>(vr, vi);
  const float scale = amp[d] * (1.0f / 4096.0f);
  float* op = out + (((size_t)b * T_ + n1) * D_) + d;
#pragma unroll
  for (int n2 = 0; n2 < 64; ++n2) op[(size_t)n2 * 64 * D_] = vr[n2] * scale;
}

extern "C" void kernel_launch(void* const* d_in, const int* in_sizes, int n_in,
                              void* d_out, int out_size, void* d_ws, size_t ws_size,
                              hipStream_t stream) {
  const float* x = (const float*)d_in[0];
  const float* W1 = (const float*)d_in[1];
  const float* b1 = (const float*)d_in[2];
  const float* W2 = (const float*)d_in[3];
  const float* b2 = (const float*)d_in[4];
  const float* amp = (const float*)d_in[5];
  float* out = (float*)d_out;

  float* h = out;              // 2049*32   = 65,568 floats
  float* Hb = out + 65568;     // 2049*1024 = 2,098,176 floats (ends < out_size)
  float2* G = (float2*)d_ws;   // [4][64][64][1024] float2 = 134,217,728 bytes

  k_filter_h<<<dim3((NBINS + 255) / 256), 256, 0, stream>>>(W1, b1, h);
  k_filter_H<<<dim3(D_ / 256, NBINS), 256, 0, stream>>>(h, W2, b2, Hb);
  k_fft_stage1<<<dim3(D_ / 256, 64, B_), 256, 0, stream>>>(x, G);
  k_fft_stage2<<<dim3(D_ / 256, 64, B_), 256, 0, stream>>>(G, Hb);
  k_fft_stage3<<<dim3(D_ / 256, 64, B_), 256, 0, stream>>>(G, amp, out);
}

// Round 3
// 224.464 us; speedup vs baseline: 1.9047x; 1.0274x over previous
//
#include <hip/hip_runtime.h>
#include <hip/hip_bf16.h>
#include <cstddef>

// Hyena1D: y = irfft(rfft(x, axis=1) * H) * amp_gain, H real per (bin, channel).
// Full complex 4096-FFT via four-step (64x64) decomposition; H extended
// symmetrically Hfull[k] = H[min(k, 4096-k)].
//
// G = float2[B][64][64][D] = 128 MB in d_ws. The (n1,k2) plane is stored
// DIAGONALLY SKEWED: value (n1,k2) lives at slot j = (k2+n1)&63 of row n1.
// Rationale: stage2 walks n1 at fixed k2 -> raw stride 64*D*8 = 512 KB, a
// power-of-2 super-stride that aliases onto the same HBM channel group
// (round-2 rocprof: stage2 168us @ 1.3 TB/s effective, VALUBusy 19%).
// Skew makes the walk 512KB+8KB per step, spreading across channels; stage3's
// fixed-n1 read over k2 becomes a row rotation (8 KB strides, benign).
//
// launch_bounds(256,1): vr[64]+vi[64] = 128 VGPRs live data; a 128-VGPR cap
// caused scratch spill (round-1: WRITE_SIZE 565 MB vs 134 ideal).

#define B_ 4
#define T_ 4096
#define D_ 1024
#define NBINS 2049

constexpr float WC[32] = {
    1.0f, 0.9951847266721969f, 0.9807852804032304f, 0.9569403357322088f,
    0.9238795325112867f, 0.8819212643483551f, 0.8314696123025452f, 0.7730104533627370f,
    0.7071067811865476f, 0.6343932841636455f, 0.5555702330196022f, 0.4713967368259976f,
    0.3826834323650898f, 0.2902846772544623f, 0.1950903220161283f, 0.0980171403295606f,
    0.0f, -0.0980171403295606f, -0.1950903220161283f, -0.2902846772544623f,
    -0.3826834323650898f, -0.4713967368259976f, -0.5555702330196022f, -0.6343932841636455f,
    -0.7071067811865476f, -0.7730104533627370f, -0.8314696123025452f, -0.8819212643483551f,
    -0.9238795325112867f, -0.9569403357322088f, -0.9807852804032304f, -0.9951847266721969f};
constexpr float WS[32] = {
    0.0f, 0.0980171403295606f, 0.1950903220161283f, 0.2902846772544623f,
    0.3826834323650898f, 0.4713967368259976f, 0.5555702330196022f, 0.6343932841636455f,
    0.7071067811865476f, 0.7730104533627370f, 0.8314696123025452f, 0.8819212643483551f,
    0.9238795325112867f, 0.9569403357322088f, 0.9807852804032304f, 0.9951847266721969f,
    1.0f, 0.9951847266721969f, 0.9807852804032304f, 0.9569403357322088f,
    0.9238795325112867f, 0.8819212643483551f, 0.8314696123025452f, 0.7730104533627370f,
    0.7071067811865476f, 0.6343932841636455f, 0.5555702330196022f, 0.4713967368259976f,
    0.3826834323650898f, 0.2902846772544623f, 0.1950903220161283f, 0.0980171403295606f};

template <int SGN>
__device__ __forceinline__ void fft64(float (&vr)[64], float (&vi)[64]) {
#pragma unroll
  for (int i = 0; i < 64; ++i) {
    const int j = ((i & 1) << 5) | ((i & 2) << 3) | ((i & 4) << 1) |
                  ((i & 8) >> 1) | ((i & 16) >> 3) | ((i & 32) >> 5);
    if (j > i) {
      float t = vr[i]; vr[i] = vr[j]; vr[j] = t;
      t = vi[i]; vi[i] = vi[j]; vi[j] = t;
    }
  }
#pragma unroll
  for (int s = 1; s <= 6; ++s) {
    const int L = 1 << s;
    const int hh = L >> 1;
    const int step = 64 >> s;
#pragma unroll
    for (int k0 = 0; k0 < 64; k0 += L) {
#pragma unroll
      for (int j = 0; j < hh; ++j) {
        const float wr = WC[j * step];
        const float wi = (float)SGN * WS[j * step];
        const int ia = k0 + j, ib = k0 + j + hh;
        const float tr = wr * vr[ib] - wi * vi[ib];
        const float ti = wr * vi[ib] + wi * vr[ib];
        vr[ib] = vr[ia] - tr;
        vi[ib] = vi[ia] - ti;
        vr[ia] += tr;
        vi[ia] += ti;
      }
    }
  }
}

// ---- filter MLP ----
__global__ void k_filter_h(const float* __restrict__ W1, const float* __restrict__ b1,
                           float* __restrict__ h) {
  const int bin = blockIdx.x * 256 + threadIdx.x;
  if (bin >= NBINS) return;
  constexpr float invf[8] = {1.0f, 0.31622776601683794f, 0.1f, 0.031622776601683794f,
                             0.01f, 3.1622776601683794e-3f, 1.0e-3f, 3.1622776601683794e-4f};
  float pe[16];
#pragma unroll
  for (int i = 0; i < 8; ++i) {
    const float a = (float)bin * invf[i];
    pe[2 * i] = sinf(a);
    pe[2 * i + 1] = cosf(a);
  }
#pragma unroll
  for (int m = 0; m < 32; ++m) {
    float s = b1[m];
#pragma unroll
    for (int i = 0; i < 16; ++i) s += pe[i] * W1[i * 32 + m];
    h[bin * 32 + m] = s / (1.0f + expf(-s));  // silu
  }
}

__global__ void k_filter_H(const float* __restrict__ h, const float* __restrict__ W2,
                           const float* __restrict__ b2, float* __restrict__ Hb) {
  const int d = blockIdx.x * 256 + threadIdx.x;
  const int bin = blockIdx.y;
  float s = b2[d];
#pragma unroll
  for (int m = 0; m < 32; ++m) s += h[bin * 32 + m] * W2[(size_t)m * D_ + d];
  Hb[(size_t)bin * D_ + d] = s;
}

// ---- stage 1: FFT over n2 (t = n1 + 64*n2) + twiddle W_4096^{n1*k2} ----
__global__ __launch_bounds__(256, 1) void k_fft_stage1(const float* __restrict__ x,
                                                       float2* __restrict__ G) {
  const int d = blockIdx.x * 256 + threadIdx.x;
  const int n1 = blockIdx.y;
  const int b = blockIdx.z;
  float vr[64], vi[64];
  const float* xp = x + (((size_t)b * T_ + n1) * D_) + d;
#pragma unroll
  for (int n2 = 0; n2 < 64; ++n2) {
    vr[n2] = xp[(size_t)n2 * 64 * D_];
    vi[n2] = 0.0f;
  }
  fft64<-1>(vr, vi);
  const float base = -(6.28318530717958647692f / 4096.0f) * (float)n1;
#pragma unroll
  for (int k2 = 1; k2 < 64; ++k2) {
    float sn, cs;
    __sincosf(base * (float)k2, &sn, &cs);
    const float r = vr[k2] * cs - vi[k2] * sn;
    const float i = vr[k2] * sn + vi[k2] * cs;
    vr[k2] = r;
    vi[k2] = i;
  }
  // skewed write: (n1,k2) -> row n1, slot (k2+n1)&63
  float2* gp = G + (((size_t)b * 64 + n1) * 64) * D_ + d;
#pragma unroll
  for (int k2 = 0; k2 < 64; ++k2)
    gp[(size_t)((k2 + n1) & 63) * D_] = make_float2(vr[k2], vi[k2]);
}

// ---- stage 2: FFT over n1 -> X[k2+64*k1]; * Hfull; inverse FFT over k1;
//      * W_4096^{-n1*k2}; in-place (per-thread addresses only) ----
__global__ __launch_bounds__(256, 1) void k_fft_stage2(float2* __restrict__ G,
                                                       const float* __restrict__ Hb) {
  const int d = blockIdx.x * 256 + threadIdx.x;
  const int k2 = blockIdx.y;
  const int b = blockIdx.z;
  float vr[64], vi[64];
  float2* gpb = G + ((size_t)b * 64 * 64) * D_ + d;
#pragma unroll
  for (int n1 = 0; n1 < 64; ++n1) {
    const float2 t = gpb[(size_t)(n1 * 64 + ((k2 + n1) & 63)) * D_];
    vr[n1] = t.x;
    vi[n1] = t.y;
  }
  fft64<-1>(vr, vi);
#pragma unroll
  for (int k1 = 0; k1 < 64; ++k1) {
    const int k = k2 + 64 * k1;
    const int km = (k <= 2048) ? k : (4096 - k);
    const float Hv = Hb[(size_t)km * D_ + d];
    vr[k1] *= Hv;
    vi[k1] *= Hv;
  }
  fft64<1>(vr, vi);
  const float base = (6.28318530717958647692f / 4096.0f) * (float)k2;
#pragma unroll
  for (int n1 = 1; n1 < 64; ++n1) {
    float sn, cs;
    __sincosf(base * (float)n1, &sn, &cs);
    const float r = vr[n1] * cs - vi[n1] * sn;
    const float i = vr[n1] * sn + vi[n1] * cs;
    vr[n1] = r;
    vi[n1] = i;
  }
#pragma unroll
  for (int n1 = 0; n1 < 64; ++n1)
    gpb[(size_t)(n1 * 64 + ((k2 + n1) & 63)) * D_] = make_float2(vr[n1], vi[n1]);
}

// ---- stage 3: inverse FFT over k2 -> y[n1 + 64*n2], scale + amp_gain ----
__global__ __launch_bounds__(256, 1) void k_fft_stage3(const float2* __restrict__ G,
                                                       const float* __restrict__ amp,
                                                       float* __restrict__ out) {
  const int d = blockIdx.x * 256 + threadIdx.x;
  const int n1 = blockIdx.y;
  const int b = blockIdx.z;
  float vr[64], vi[64];
  const float2* gp = G + (((size_t)b * 64 + n1) * 64) * D_ + d;
#pragma unroll
  for (int k2 = 0; k2 < 64; ++k2) {
    const float2 t = gp[(size_t)((k2 + n1) & 63) * D_];
    vr[k2] = t.x;
    vi[k2] = t.y;
  }
  fft64<1>(vr, vi);
  const float scale = amp[d] * (1.0f / 4096.0f);
  float* op = out + (((size_t)b * T_ + n1) * D_) + d;
#pragma unroll
  for (int n2 = 0; n2 < 64; ++n2) op[(size_t)n2 * 64 * D_] = vr[n2] * scale;
}

extern "C" void kernel_launch(void* const* d_in, const int* in_sizes, int n_in,
                              void* d_out, int out_size, void* d_ws, size_t ws_size,
                              hipStream_t stream) {
  const float* x = (const float*)d_in[0];
  const float* W1 = (const float*)d_in[1];
  const float* b1 = (const float*)d_in[2];
  const float* W2 = (const float*)d_in[3];
  const float* b2 = (const float*)d_in[4];
  const float* amp = (const float*)d_in[5];
  float* out = (float*)d_out;

  float* h = out;              // 2049*32   = 65,568 floats
  float* Hb = out + 65568;     // 2049*1024 = 2,098,176 floats (ends < out_size)
  float2* G = (float2*)d_ws;   // [4][64][64][1024] float2 = 134,217,728 bytes

  k_filter_h<<<dim3((NBINS + 255) / 256), 256, 0, stream>>>(W1, b1, h);
  k_filter_H<<<dim3(D_ / 256, NBINS), 256, 0, stream>>>(h, W2, b2, Hb);
  k_fft_stage1<<<dim3(D_ / 256, 64, B_), 256, 0, stream>>>(x, G);
  k_fft_stage2<<<dim3(D_ / 256, 64, B_), 256, 0, stream>>>(G, Hb);
  k_fft_stage3<<<dim3(D_ / 256, 64, B_), 256, 0, stream>>>(G, amp, out);
}

// Round 4
// 219.087 us; speedup vs baseline: 1.9514x; 1.0245x over previous
//
#include <hip/hip_runtime.h>
#include <hip/hip_bf16.h>
#include <cstddef>

// Hyena1D: y = irfft(rfft(x, axis=1) * H) * amp_gain, H real per (bin, channel).
//
// Channel-PAIR packing: z_g(t) = x[t][2g] + i*x[t][2g+1]  (g in [0,512)).
// One complex 4096-FFT serves two real channels. Filtering both with their own
// real H via conjugate symmetry:
//   Y[k] = hp*Z[k] + hm*conj(Z[N-k]),  hp = (HA+HB)/2, hm = (HA-HB)/2
// Then ifft(Y) = yA + i*yB directly. Halves all traffic vs unpacked (G: 64 MB).
//
// Four-step 4096 = 64x64: stage1 FFT over n2 + twiddle -> G[b][n1][k2][g];
// stage2 FFT over n1, filter (needs Z[N-k]: k2 pairs with 64-k2 -> both k2
// columns in one block, LDS chunk exchange; k2=0,32 self-paired in-register),
// iFFT over k1 + twiddle -> A[b][m1][k2][g] OUT-OF-PLACE (A = G + 64MB);
// stage3 iFFT over k2 -> y, * amp/4096.
//
// Round-3 forensics: stage1/stage3 (strided reads ~256KB + separate write
// region) ran near HBM peak; only stage2 (512KB-stride in-place RMW) collapsed
// (160us @ 1.6 TB/s). This version halves stage2's stride to the proven-fast
// 256KB class, decouples R/W regions, and halves traffic.
//
// launch_bounds(256,1): 128 VGPRs of live FFT data/thread; a 128-cap spills
// (round-1: 565MB scratch writes). ws needed: 128 MB.

#define B_ 4
#define T_ 4096
#define D_ 1024
#define D2_ 512
#define NBINS 2049

constexpr float WC[32] = {
    1.0f, 0.9951847266721969f, 0.9807852804032304f, 0.9569403357322088f,
    0.9238795325112867f, 0.8819212643483551f, 0.8314696123025452f, 0.7730104533627370f,
    0.7071067811865476f, 0.6343932841636455f, 0.5555702330196022f, 0.4713967368259976f,
    0.3826834323650898f, 0.2902846772544623f, 0.1950903220161283f, 0.0980171403295606f,
    0.0f, -0.0980171403295606f, -0.1950903220161283f, -0.2902846772544623f,
    -0.3826834323650898f, -0.4713967368259976f, -0.5555702330196022f, -0.6343932841636455f,
    -0.7071067811865476f, -0.7730104533627370f, -0.8314696123025452f, -0.8819212643483551f,
    -0.9238795325112867f, -0.9569403357322088f, -0.9807852804032304f, -0.9951847266721969f};
constexpr float WS[32] = {
    0.0f, 0.0980171403295606f, 0.1950903220161283f, 0.2902846772544623f,
    0.3826834323650898f, 0.4713967368259976f, 0.5555702330196022f, 0.6343932841636455f,
    0.7071067811865476f, 0.7730104533627370f, 0.8314696123025452f, 0.8819212643483551f,
    0.9238795325112867f, 0.9569403357322088f, 0.9807852804032304f, 0.9951847266721969f,
    1.0f, 0.9951847266721969f, 0.9807852804032304f, 0.9569403357322088f,
    0.9238795325112867f, 0.8819212643483551f, 0.8314696123025452f, 0.7730104533627370f,
    0.7071067811865476f, 0.6343932841636455f, 0.5555702330196022f, 0.4713967368259976f,
    0.3826834323650898f, 0.2902846772544623f, 0.1950903220161283f, 0.0980171403295606f};

template <int SGN>
__device__ __forceinline__ void fft64(float (&vr)[64], float (&vi)[64]) {
#pragma unroll
  for (int i = 0; i < 64; ++i) {
    const int j = ((i & 1) << 5) | ((i & 2) << 3) | ((i & 4) << 1) |
                  ((i & 8) >> 1) | ((i & 16) >> 3) | ((i & 32) >> 5);
    if (j > i) {
      float t = vr[i]; vr[i] = vr[j]; vr[j] = t;
      t = vi[i]; vi[i] = vi[j]; vi[j] = t;
    }
  }
#pragma unroll
  for (int s = 1; s <= 6; ++s) {
    const int L = 1 << s;
    const int hh = L >> 1;
    const int step = 64 >> s;
#pragma unroll
    for (int k0 = 0; k0 < 64; k0 += L) {
#pragma unroll
      for (int j = 0; j < hh; ++j) {
        const float wr = WC[j * step];
        const float wi = (float)SGN * WS[j * step];
        const int ia = k0 + j, ib = k0 + j + hh;
        const float tr = wr * vr[ib] - wi * vi[ib];
        const float ti = wr * vi[ib] + wi * vr[ib];
        vr[ib] = vr[ia] - tr;
        vi[ib] = vi[ia] - ti;
        vr[ia] += tr;
        vi[ia] += ti;
      }
    }
  }
}

// ---- filter MLP ----
__global__ void k_filter_h(const float* __restrict__ W1, const float* __restrict__ b1,
                           float* __restrict__ h) {
  const int bin = blockIdx.x * 256 + threadIdx.x;
  if (bin >= NBINS) return;
  constexpr float invf[8] = {1.0f, 0.31622776601683794f, 0.1f, 0.031622776601683794f,
                             0.01f, 3.1622776601683794e-3f, 1.0e-3f, 3.1622776601683794e-4f};
  float pe[16];
#pragma unroll
  for (int i = 0; i < 8; ++i) {
    const float a = (float)bin * invf[i];
    pe[2 * i] = sinf(a);
    pe[2 * i + 1] = cosf(a);
  }
#pragma unroll
  for (int m = 0; m < 32; ++m) {
    float s = b1[m];
#pragma unroll
    for (int i = 0; i < 16; ++i) s += pe[i] * W1[i * 32 + m];
    h[bin * 32 + m] = s / (1.0f + expf(-s));  // silu
  }
}

__global__ void k_filter_H(const float* __restrict__ h, const float* __restrict__ W2,
                           const float* __restrict__ b2, float* __restrict__ Hb) {
  const int d = blockIdx.x * 256 + threadIdx.x;
  const int bin = blockIdx.y;
  float s = b2[d];
#pragma unroll
  for (int m = 0; m < 32; ++m) s += h[bin * 32 + m] * W2[(size_t)m * D_ + d];
  Hb[(size_t)bin * D_ + d] = s;
}

// ---- stage 1: packed load, FFT over n2, twiddle W^{-n1*k2} -> G[b][n1][k2][g] ----
__global__ __launch_bounds__(256, 1) void k_fft_stage1(const float2* __restrict__ x2,
                                                       float2* __restrict__ G) {
  const int g = blockIdx.x * 256 + threadIdx.x;
  const int n1 = blockIdx.y;
  const int b = blockIdx.z;
  float vr[64], vi[64];
  const float2* xp = x2 + ((size_t)b * T_ + n1) * D2_ + g;
#pragma unroll
  for (int n2 = 0; n2 < 64; ++n2) {
    const float2 t = xp[(size_t)n2 * 64 * D2_];
    vr[n2] = t.x;
    vi[n2] = t.y;
  }
  fft64<-1>(vr, vi);
  const float base = -(6.28318530717958647692f / 4096.0f) * (float)n1;
#pragma unroll
  for (int k2 = 1; k2 < 64; ++k2) {
    float sn, cs;
    __sincosf(base * (float)k2, &sn, &cs);
    const float r = vr[k2] * cs - vi[k2] * sn;
    const float i = vr[k2] * sn + vi[k2] * cs;
    vr[k2] = r;
    vi[k2] = i;
  }
  float2* gp = G + (((size_t)b * 64 + n1) * 64) * D2_ + g;
#pragma unroll
  for (int k2 = 0; k2 < 64; ++k2) gp[(size_t)k2 * D2_] = make_float2(vr[k2], vi[k2]);
}

// ---- stage 2: FFT over n1; packed-pair filter; iFFT over k1; twiddle; -> A ----
__global__ __launch_bounds__(256, 1) void k_fft_stage2(const float2* __restrict__ G,
                                                       float2* __restrict__ A,
                                                       const float2* __restrict__ Hb2) {
  __shared__ float2 xch[2][128][17];  // [j][gl][slot], padded (34 KB)
  const int tid = threadIdx.x;
  const int j = tid >> 7;  // wave-uniform half select
  const int gl = tid & 127;
  const int g = blockIdx.x * 128 + gl;
  const int p = blockIdx.y;  // pair index: {0,32} self, else {p, 64-p}
  const int b = blockIdx.z;
  const int k2 = (p == 0) ? (j ? 32 : 0) : (j ? (64 - p) : p);

  float vr[64], vi[64];
  const float2* gp = G + ((size_t)b * 64 * 64 + k2) * D2_ + g;
#pragma unroll
  for (int n1 = 0; n1 < 64; ++n1) {
    const float2 t = gp[(size_t)n1 * 64 * D2_];
    vr[n1] = t.x;
    vi[n1] = t.y;
  }
  fft64<-1>(vr, vi);  // -> Z[k1] = X[k2 + 64*k1]

  if (p == 0) {
    if (j == 0) {  // k2 = 0: self slots 0, 32; pairs (a, 64-a)
      {
        const float2 Hv = Hb2[g];  // km = 0
        const float hp = 0.5f * (Hv.x + Hv.y), hm = 0.5f * (Hv.x - Hv.y);
        const float re = vr[0], im = vi[0];
        vr[0] = (hp + hm) * re;
        vi[0] = (hp - hm) * im;
      }
      {
        const float2 Hv = Hb2[(size_t)2048 * D2_ + g];  // km = 2048
        const float hp = 0.5f * (Hv.x + Hv.y), hm = 0.5f * (Hv.x - Hv.y);
        const float re = vr[32], im = vi[32];
        vr[32] = (hp + hm) * re;
        vi[32] = (hp - hm) * im;
      }
#pragma unroll
      for (int a = 1; a < 32; ++a) {
        const int bb = 64 - a;
        const float2 Hv = Hb2[(size_t)(64 * a) * D2_ + g];  // km = 64a (<=1984)
        const float hp = 0.5f * (Hv.x + Hv.y), hm = 0.5f * (Hv.x - Hv.y);
        const float zar = vr[a], zai = vi[a], zbr = vr[bb], zbi = vi[bb];
        vr[a] = hp * zar + hm * zbr;
        vi[a] = hp * zai - hm * zbi;
        vr[bb] = hp * zbr + hm * zar;
        vi[bb] = hp * zbi - hm * zai;
      }
    } else {  // k2 = 32: pairs (a, 63-a)
#pragma unroll
      for (int a = 0; a < 32; ++a) {
        const int bb = 63 - a;
        const int k = 32 + 64 * a;  // <= 2016, km = k
        const float2 Hv = Hb2[(size_t)k * D2_ + g];
        const float hp = 0.5f * (Hv.x + Hv.y), hm = 0.5f * (Hv.x - Hv.y);
        const float zar = vr[a], zai = vi[a], zbr = vr[bb], zbi = vi[bb];
        vr[a] = hp * zar + hm * zbr;
        vi[a] = hp * zai - hm * zbi;
        vr[bb] = hp * zbr + hm * zar;
        vi[bb] = hp * zbi - hm * zai;
      }
    }
  } else {
    // partner thread: (gl, j^1) holds k2' = 64-k2; needed slot is 63-k1.
    // Round c: j=0 writes+processes its chunk c; j=1 its chunk 3-c.
#pragma unroll
    for (int c = 0; c < 4; ++c) {
      if (j == 0) {
#pragma unroll
        for (int s = 0; s < 16; ++s)
          xch[0][gl][s] = make_float2(vr[16 * c + s], vi[16 * c + s]);
      } else {
#pragma unroll
        for (int s = 0; s < 16; ++s)
          xch[1][gl][s] = make_float2(vr[16 * (3 - c) + s], vi[16 * (3 - c) + s]);
      }
      __syncthreads();
      if (j == 0) {
#pragma unroll
        for (int s = 0; s < 16; ++s) {
          const int k1 = 16 * c + s;
          const int k = k2 + 64 * k1;
          const int km = (k <= 2048) ? k : 4096 - k;
          const float2 Hv = Hb2[(size_t)km * D2_ + g];
          const float hp = 0.5f * (Hv.x + Hv.y), hm = 0.5f * (Hv.x - Hv.y);
          const float2 zb = xch[1][gl][15 - s];
          const float zar = vr[k1], zai = vi[k1];
          vr[k1] = hp * zar + hm * zb.x;
          vi[k1] = hp * zai - hm * zb.y;
        }
      } else {
#pragma unroll
        for (int s = 0; s < 16; ++s) {
          const int k1 = 16 * (3 - c) + s;
          const int k = k2 + 64 * k1;
          const int km = (k <= 2048) ? k : 4096 - k;
          const float2 Hv = Hb2[(size_t)km * D2_ + g];
          const float hp = 0.5f * (Hv.x + Hv.y), hm = 0.5f * (Hv.x - Hv.y);
          const float2 zb = xch[0][gl][15 - s];
          const float zar = vr[k1], zai = vi[k1];
          vr[k1] = hp * zar + hm * zb.x;
          vi[k1] = hp * zai - hm * zb.y;
        }
      }
      __syncthreads();
    }
  }

  fft64<1>(vr, vi);  // iFFT over k1 -> m1
  const float base = (6.28318530717958647692f / 4096.0f) * (float)k2;
#pragma unroll
  for (int m1 = 1; m1 < 64; ++m1) {
    float sn, cs;
    __sincosf(base * (float)m1, &sn, &cs);
    const float r = vr[m1] * cs - vi[m1] * sn;
    const float i2 = vr[m1] * sn + vi[m1] * cs;
    vr[m1] = r;
    vi[m1] = i2;
  }
  float2* ap = A + ((size_t)b * 64 * 64 + k2) * D2_ + g;
#pragma unroll
  for (int m1 = 0; m1 < 64; ++m1) ap[(size_t)m1 * 64 * D2_] = make_float2(vr[m1], vi[m1]);
}

// ---- stage 3: iFFT over k2 -> time, unpack Re/Im to channel pair, scale ----
__global__ __launch_bounds__(256, 1) void k_fft_stage3(const float2* __restrict__ A,
                                                       const float2* __restrict__ amp2,
                                                       float2* __restrict__ out2) {
  const int g = blockIdx.x * 256 + threadIdx.x;
  const int m1 = blockIdx.y;
  const int b = blockIdx.z;
  float vr[64], vi[64];
  const float2* ap = A + (((size_t)b * 64 + m1) * 64) * D2_ + g;
#pragma unroll
  for (int k2 = 0; k2 < 64; ++k2) {
    const float2 t = ap[(size_t)k2 * D2_];
    vr[k2] = t.x;
    vi[k2] = t.y;
  }
  fft64<1>(vr, vi);
  const float2 av = amp2[g];
  const float sA = av.x * (1.0f / 4096.0f);
  const float sB = av.y * (1.0f / 4096.0f);
  float2* op = out2 + ((size_t)b * T_ + m1) * D2_ + g;
#pragma unroll
  for (int m2 = 0; m2 < 64; ++m2)
    op[(size_t)m2 * 64 * D2_] = make_float2(vr[m2] * sA, vi[m2] * sB);
}

extern "C" void kernel_launch(void* const* d_in, const int* in_sizes, int n_in,
                              void* d_out, int out_size, void* d_ws, size_t ws_size,
                              hipStream_t stream) {
  const float* x = (const float*)d_in[0];
  const float* W1 = (const float*)d_in[1];
  const float* b1 = (const float*)d_in[2];
  const float* W2 = (const float*)d_in[3];
  const float* b2 = (const float*)d_in[4];
  const float* amp = (const float*)d_in[5];
  float* out = (float*)d_out;

  float* h = out;           // 2049*32 floats staged in d_out
  float* Hb = out + 65568;  // 2049*1024 floats (overwritten by stage3 later)
  float2* G = (float2*)d_ws;                       // 64 MB
  float2* A = (float2*)d_ws + (size_t)B_ * 64 * 64 * D2_;  // +64 MB

  k_filter_h<<<dim3((NBINS + 255) / 256), 256, 0, stream>>>(W1, b1, h);
  k_filter_H<<<dim3(D_ / 256, NBINS), 256, 0, stream>>>(h, W2, b2, Hb);
  k_fft_stage1<<<dim3(D2_ / 256, 64, B_), 256, 0, stream>>>((const float2*)x, G);
  k_fft_stage2<<<dim3(D2_ / 128, 32, B_), 256, 0, stream>>>(G, A, (const float2*)Hb);
  k_fft_stage3<<<dim3(D2_ / 256, 64, B_), 256, 0, stream>>>(A, (const float2*)amp, (float2*)out);
}

// Round 5
// 120.337 us; speedup vs baseline: 3.5528x; 1.8206x over previous
//
#include <hip/hip_runtime.h>
#include <hip/hip_bf16.h>
#include <cstddef>

// Hyena1D: y = irfft(rfft(x, axis=1) * H) * amp_gain, H real per (bin, channel).
//
// Channel-pair packing (validated r4): z_g(t) = x[t][2g] + i*x[t][2g+1];
//   Y[k] = hp*Z[k] + hm*conj(Z[N-k]), hp=(HA+HB)/2, hm=(HA-HB)/2 (1/N folded in).
//
// r4 forensics: four-step over HBM with power-of-2 far strides on BOTH r/w
// sides runs at <1 TB/s effective regardless of skew. This version removes
// strided HBM entirely:
//   T1: tile-transpose x[b,t,d] -> Z[b,g,t] (both sides coalesced via LDS)
//   F : one block per (b,g): full 4096 FFT -> filter -> iFFT in 32KB LDS,
//       radix-16 x 3 (DIF fwd, scrambled-order filter, DIT inv), contiguous
//       global r/w only.
//   T2: tile-transpose back + amp_gain.
// ws: Z 64MB @0; HT[g][bin] (hp,hm) 8.4MB @64MB; h 262KB after. (<76MB)

#define B_ 4
#define T_ 4096
#define D_ 1024
#define D2_ 512
#define NBINS 2049

constexpr float WC16[8] = {1.f, 0.9238795325112867f, 0.7071067811865476f,
                           0.3826834323650898f, 0.f, -0.3826834323650898f,
                           -0.7071067811865476f, -0.9238795325112867f};
constexpr float WS16[8] = {0.f, 0.3826834323650898f, 0.7071067811865476f,
                           0.9238795325112867f, 1.f, 0.9238795325112867f,
                           0.7071067811865476f, 0.3826834323650898f};

// 16-point DFT, radix-2, fully unrolled. SGN=-1 fwd (e^{-i}), +1 inv.
template <int SGN>
__device__ __forceinline__ void dft16(float (&vr)[16], float (&vi)[16]) {
#pragma unroll
  for (int i = 0; i < 16; ++i) {
    const int j = ((i & 1) << 3) | ((i & 2) << 1) | ((i & 4) >> 1) | ((i & 8) >> 3);
    if (j > i) {
      float t = vr[i]; vr[i] = vr[j]; vr[j] = t;
      t = vi[i]; vi[i] = vi[j]; vi[j] = t;
    }
  }
#pragma unroll
  for (int s = 1; s <= 4; ++s) {
    const int L = 1 << s, hh = L >> 1, step = 16 >> s;
#pragma unroll
    for (int k0 = 0; k0 < 16; k0 += L)
#pragma unroll
      for (int j = 0; j < hh; ++j) {
        const float wr = WC16[j * step];
        const float wi = (float)SGN * WS16[j * step];
        const int ia = k0 + j, ib = ia + hh;
        const float tr = wr * vr[ib] - wi * vi[ib];
        const float ti = wr * vi[ib] + wi * vr[ib];
        vr[ib] = vr[ia] - tr; vi[ib] = vi[ia] - ti;
        vr[ia] += tr; vi[ia] += ti;
      }
  }
}

__device__ __forceinline__ void twiddle(float& xr, float& xi, float ang) {
  float sn, cs;
  __sincosf(ang, &sn, &cs);
  const float r = xr * cs - xi * sn;
  xi = xr * sn + xi * cs;
  xr = r;
}

// ---- filter MLP ----
__global__ void k_filter_h(const float* __restrict__ W1, const float* __restrict__ b1,
                           float* __restrict__ h) {
  const int bin = blockIdx.x * 256 + threadIdx.x;
  if (bin >= NBINS) return;
  constexpr float invf[8] = {1.0f, 0.31622776601683794f, 0.1f, 0.031622776601683794f,
                             0.01f, 3.1622776601683794e-3f, 1.0e-3f, 3.1622776601683794e-4f};
  float pe[16];
#pragma unroll
  for (int i = 0; i < 8; ++i) {
    const float a = (float)bin * invf[i];
    pe[2 * i] = sinf(a);
    pe[2 * i + 1] = cosf(a);
  }
#pragma unroll
  for (int m = 0; m < 32; ++m) {
    float s = b1[m];
#pragma unroll
    for (int i = 0; i < 16; ++i) s += pe[i] * W1[i * 32 + m];
    h[bin * 32 + m] = s / (1.0f + expf(-s));  // silu
  }
}

// HT[g][bin] = (hp, hm) pre-scaled by 1/4096
__global__ void k_filter_HT(const float* __restrict__ h, const float* __restrict__ W2,
                            const float* __restrict__ b2, float2* __restrict__ HT) {
  const int bin = blockIdx.x * 256 + threadIdx.x;
  const int g = blockIdx.y;
  if (bin >= NBINS) return;
  float sA = b2[2 * g], sB = b2[2 * g + 1];
#pragma unroll
  for (int m = 0; m < 32; ++m) {
    const float hv = h[bin * 32 + m];
    sA += hv * W2[m * D_ + 2 * g];
    sB += hv * W2[m * D_ + 2 * g + 1];
  }
  constexpr float sc = 0.5f / 4096.0f;
  HT[(size_t)g * NBINS + bin] = make_float2((sA + sB) * sc, (sA - sB) * sc);
}

// ---- T1: x[b,t,d] -> Z[b,g,t] (packed pairs) ----
__global__ __launch_bounds__(256, 8) void k_pack_t(const float2* __restrict__ x2,
                                                   float2* __restrict__ Z) {
  __shared__ float2 tile[64][33];
  const int tid = threadIdx.x;
  const int g0 = blockIdx.x * 32;
  const int t0 = blockIdx.y * 64;
  const int b = blockIdx.z;
#pragma unroll
  for (int it = 0; it < 8; ++it) {
    const int l = tid + 256 * it;
    const int r = l >> 5, c = l & 31;
    tile[r][c] = x2[((size_t)b * T_ + t0 + r) * D2_ + g0 + c];
  }
  __syncthreads();
#pragma unroll
  for (int it = 0; it < 8; ++it) {
    const int l = tid + 256 * it;
    const int gg = l >> 6, tt = l & 63;
    Z[((size_t)b * D2_ + g0 + gg) * T_ + t0 + tt] = tile[tt][gg];
  }
}

// ---- F: full FFT/filter/iFFT per (g,b), in-place on Z row ----
__global__ __launch_bounds__(256, 4) void k_fft_fused(float2* __restrict__ Z,
                                                      const float2* __restrict__ HT) {
  __shared__ float2 S[4096];
  const int tid = threadIdx.x;
  const int g = blockIdx.x;
  const int b = blockIdx.y;
  float2* __restrict__ Zrow = Z + ((size_t)b * D2_ + g) * T_;
  const float2* __restrict__ HTg = HT + (size_t)g * NBINS;
  constexpr float C1f = -6.28318530717958647692f / 4096.0f;
  constexpr float C2f = -6.28318530717958647692f / 256.0f;
  constexpr float C1i = 6.28318530717958647692f / 4096.0f;
  constexpr float C2i = 6.28318530717958647692f / 256.0f;

  float vr[16], vi[16];
  // fwd stage 1: thread j: u[a]=z[j+256a]; DFT16 a->r; *W4096^{-rj}; S[256r+j]
  {
    const int j = tid;
#pragma unroll
    for (int a = 0; a < 16; ++a) {
      const float2 t = Zrow[j + 256 * a];
      vr[a] = t.x; vi[a] = t.y;
    }
    dft16<-1>(vr, vi);
#pragma unroll
    for (int r = 1; r < 16; ++r) twiddle(vr[r], vi[r], C1f * (float)(r * j));
#pragma unroll
    for (int r = 0; r < 16; ++r) S[256 * r + j] = make_float2(vr[r], vi[r]);
  }
  __syncthreads();
  const int rr = tid >> 4, ii = tid & 15;
  // fwd stage 2: thread (r=rr, i=ii): u[a]=V[rr][ii+16a]; DFT16 a->r2;
  // *W256^{-r2*ii}; S[256*ii + 16*rr + (r2^ii)]
  {
#pragma unroll
    for (int a = 0; a < 16; ++a) {
      const float2 t = S[256 * rr + ii + 16 * a];
      vr[a] = t.x; vi[a] = t.y;
    }
    __syncthreads();  // WAR
    dft16<-1>(vr, vi);
#pragma unroll
    for (int r2 = 1; r2 < 16; ++r2) twiddle(vr[r2], vi[r2], C2f * (float)(r2 * ii));
#pragma unroll
    for (int r2 = 0; r2 < 16; ++r2)
      S[256 * ii + 16 * rr + (r2 ^ ii)] = make_float2(vr[r2], vi[r2]);
  }
  __syncthreads();
  // fwd stage 3: thread (r=rr, r2=ii): u[i]=V2 at S[256i+16rr+(ii^i)];
  // DFT16 i->s2  => vr[s2] = X[k], k = rr + 16*ii + 256*s2
  {
#pragma unroll
    for (int i2 = 0; i2 < 16; ++i2) {
      const float2 t = S[256 * i2 + 16 * rr + (ii ^ i2)];
      vr[i2] = t.x; vi[i2] = t.y;
    }
    __syncthreads();  // WAR
    dft16<-1>(vr, vi);
  }
  // filter: X stored natural-swizzled Q(k)=256*d2+16*d1+(d0^d1); partner conj
  float2 hv[16];
  {
#pragma unroll
    for (int s2 = 0; s2 < 16; ++s2) {
      const int k = rr + 16 * ii + 256 * s2;
      const int km = (k <= 2048) ? k : 4096 - k;
      hv[s2] = HTg[km];
    }
#pragma unroll
    for (int s2 = 0; s2 < 16; ++s2)
      S[256 * s2 + 16 * ii + (rr ^ ii)] = make_float2(vr[s2], vi[s2]);
    __syncthreads();
#pragma unroll
    for (int s2 = 0; s2 < 16; ++s2) {
      const int k = rr + 16 * ii + 256 * s2;
      const int kp = (4096 - k) & 4095;
      const int d0 = kp & 15, d1 = (kp >> 4) & 15, d2 = kp >> 8;
      const float2 xp = S[256 * d2 + 16 * d1 + (d0 ^ d1)];
      const float yr = hv[s2].x * vr[s2] + hv[s2].y * xp.x;
      const float yi = hv[s2].x * vi[s2] - hv[s2].y * xp.y;
      vr[s2] = yr; vi[s2] = yi;
    }
  }
  __syncthreads();  // WAR before P4 writes
  // inv stage A (registers): DFT16 s2->j0; *W256^{+ii*j0}; S[256j0+16rr+(ii^j0)]
  {
    dft16<1>(vr, vi);
#pragma unroll
    for (int j0 = 1; j0 < 16; ++j0) twiddle(vr[j0], vi[j0], C2i * (float)(ii * j0));
#pragma unroll
    for (int j0 = 0; j0 < 16; ++j0)
      S[256 * j0 + 16 * rr + (ii ^ j0)] = make_float2(vr[j0], vi[j0]);
  }
  __syncthreads();
  // inv stage B: thread (r'=rr, j0'=ii): u[r2]=S[256*ii+16*rr+(r2^ii)];
  // DFT16 r2->j1; *W4096^{+rr*(ii+16*j1)}; C at S[256*rr + ii + 16*j1]
  {
#pragma unroll
    for (int r2 = 0; r2 < 16; ++r2) {
      const float2 t = S[256 * ii + 16 * rr + (r2 ^ ii)];
      vr[r2] = t.x; vi[r2] = t.y;
    }
    __syncthreads();  // WAR
    dft16<1>(vr, vi);
#pragma unroll
    for (int j1 = 0; j1 < 16; ++j1)
      twiddle(vr[j1], vi[j1], C1i * (float)(rr * (ii + 16 * j1)));
#pragma unroll
    for (int j1 = 0; j1 < 16; ++j1)
      S[256 * rr + ii + 16 * j1] = make_float2(vr[j1], vi[j1]);
  }
  __syncthreads();
  // inv stage C: thread j: u[r]=S[256r+j]; DFT16 r->a; z[j+256a] (1/N in HT)
  {
    const int j = tid;
#pragma unroll
    for (int r = 0; r < 16; ++r) {
      const float2 t = S[256 * r + j];
      vr[r] = t.x; vi[r] = t.y;
    }
    dft16<1>(vr, vi);
#pragma unroll
    for (int a = 0; a < 16; ++a) Zrow[j + 256 * a] = make_float2(vr[a], vi[a]);
  }
}

// ---- T2: Z[b,g,t] -> y[b,t,d], * amp ----
__global__ __launch_bounds__(256, 8) void k_unpack_t(const float2* __restrict__ Z,
                                                     const float2* __restrict__ amp2,
                                                     float2* __restrict__ y2) {
  __shared__ float2 tile[64][33];
  const int tid = threadIdx.x;
  const int g0 = blockIdx.x * 32;
  const int t0 = blockIdx.y * 64;
  const int b = blockIdx.z;
#pragma unroll
  for (int it = 0; it < 8; ++it) {
    const int l = tid + 256 * it;
    const int gg = l >> 6, tt = l & 63;
    tile[tt][gg] = Z[((size_t)b * D2_ + g0 + gg) * T_ + t0 + tt];
  }
  __syncthreads();
#pragma unroll
  for (int it = 0; it < 8; ++it) {
    const int l = tid + 256 * it;
    const int r = l >> 5, c = l & 31;
    const float2 t = tile[r][c];
    const float2 av = amp2[g0 + c];
    y2[((size_t)b * T_ + t0 + r) * D2_ + g0 + c] = make_float2(t.x * av.x, t.y * av.y);
  }
}

extern "C" void kernel_launch(void* const* d_in, const int* in_sizes, int n_in,
                              void* d_out, int out_size, void* d_ws, size_t ws_size,
                              hipStream_t stream) {
  const float* x = (const float*)d_in[0];
  const float* W1 = (const float*)d_in[1];
  const float* b1 = (const float*)d_in[2];
  const float* W2 = (const float*)d_in[3];
  const float* b2 = (const float*)d_in[4];
  const float* amp = (const float*)d_in[5];
  float* out = (float*)d_out;

  float2* Z = (float2*)d_ws;  // 4*512*4096*8 = 64 MB
  float2* HT = (float2*)((char*)d_ws + (size_t)B_ * D2_ * T_ * sizeof(float2));  // 8.4 MB
  float* h = (float*)((char*)HT + (size_t)D2_ * NBINS * sizeof(float2));  // 262 KB

  k_filter_h<<<dim3((NBINS + 255) / 256), 256, 0, stream>>>(W1, b1, h);
  k_filter_HT<<<dim3((NBINS + 255) / 256, D2_), 256, 0, stream>>>(h, W2, b2, HT);
  k_pack_t<<<dim3(D2_ / 32, T_ / 64, B_), 256, 0, stream>>>((const float2*)x, Z);
  k_fft_fused<<<dim3(D2_, B_), 256, 0, stream>>>(Z, HT);
  k_unpack_t<<<dim3(D2_ / 32, T_ / 64, B_), 256, 0, stream>>>(Z, (const float2*)amp,
                                                              (float2*)out);
}